// Round 3
// baseline (236.596 us; speedup 1.0000x reference)
//
#include <hip/hip_runtime.h>
#include <stdint.h>
#include <stddef.h>

#define NPIX  1024
#define DHID  128
#define CIN   256

typedef _Float16 f16;
typedef __attribute__((ext_vector_type(4))) _Float16 f16x4;
typedef __attribute__((ext_vector_type(8))) _Float16 f16x8;
typedef __attribute__((ext_vector_type(4))) float f32x4;
typedef __attribute__((ext_vector_type(16))) float f32x16;

#define MFMA16(a,b,c) __builtin_amdgcn_mfma_f32_16x16x32_f16((a),(b),(c),0,0,0)
#define MFMA32(a,b,c) __builtin_amdgcn_mfma_f32_32x32x16_f16((a),(b),(c),0,0,0)

typedef const __attribute__((address_space(1))) uint32_t GU32;
typedef __attribute__((address_space(3))) uint32_t LU32;

__device__ __forceinline__ void gll16(const void* g, void* l) {
  __builtin_amdgcn_global_load_lds((GU32*)g, (LU32*)l, 16, 0, 0);
}

// ---------------------------------------------------------------------------
// Kernel 0: W fp32 -> fp16
// ---------------------------------------------------------------------------
__global__ void wprep_kernel(const float* __restrict__ Wq, const float* __restrict__ Wk,
                             f16* __restrict__ Whq, f16* __restrict__ Whk) {
  int i = blockIdx.x * 256 + threadIdx.x;
  if (i < DHID * CIN) { Whq[i] = (f16)Wq[i]; Whk[i] = (f16)Wk[i]; }
}

// ---------------------------------------------------------------------------
// Kernel 1: projection. Block = 64 pixels x full 256c, 4 waves.
// ONE bulk stage phase (fused out-copy + V cast) -> one barrier -> 64 MFMA16
// per wave -> transpose epilogue. X staged TRANSPOSED in LDS [p][c] so
// B-frags are contiguous ds_read_b128.
// ---------------------------------------------------------------------------
__global__ __launch_bounds__(256) void proj_kernel(
    const float* __restrict__ Xl, const float* __restrict__ Xr,
    const f16* __restrict__ Whq, const f16* __restrict__ Whk,
    const float* __restrict__ bq, const float* __restrict__ bk,
    f16* __restrict__ QT, f16* __restrict__ KT,
    float* __restrict__ out, f16* __restrict__ Vb)
{
  __shared__ char smem[64 * 264 * 2];        // 33792 B: sXT [64p][264c] / sO union
  f16* sXT = (f16*)smem;
  f16* sO  = (f16*)smem;                     // [64p][136d] (17408 B)

  const int tid = threadIdx.x;
  const int w = tid >> 6, lane = tid & 63, g = lane >> 4, r16 = lane & 15;
  const int p0 = blockIdx.x * 64, b = blockIdx.y;
  const bool isK = (blockIdx.z != 0);

  const float* X = (isK ? Xr : Xl) + (size_t)b * CIN * NPIX;
  const f16* Wh = isK ? Whk : Whq;
  const float* bias = isK ? bk : bq;
  f16* QKT = (isK ? KT : QT) + (size_t)b * NPIX * DHID;

  // ---- bulk stage: X panel 256c x 64p, fused side outputs ----
  const int cl = tid >> 4;            // 0..15
  const int p4 = (tid & 15) * 4;
  const int csw = (tid & 3) << 3;     // swizzle = ((p>>2)&3)<<3, p4>>2 & 3 == tid&3
#pragma unroll
  for (int i = 0; i < 16; ++i) {
    int c = cl + 16 * i;
    f32x4 v = *(const f32x4*)(X + (size_t)c * NPIX + p0 + p4);
    if (!isK) *(f32x4*)(out + ((size_t)b * 2 * CIN + c) * NPIX + p0 + p4) = v;
    f16x4 hv = {(f16)v.x, (f16)v.y, (f16)v.z, (f16)v.w};
    if (isK) *(f16x4*)(Vb + ((size_t)b * CIN + c) * NPIX + p0 + p4) = hv;
    int cs = c ^ csw;
#pragma unroll
    for (int j = 0; j < 4; ++j) sXT[(p4 + j) * 264 + cs] = hv[j];
  }
  __syncthreads();

  // ---- B-frags: contiguous 16B reads from sXT row (p = 16w + r16) ----
  const int prow = 16 * w + r16;
  const int swzp = ((r16 >> 2) & 3) << 3;
  f16x8 xb[8];
#pragma unroll
  for (int kc = 0; kc < 8; ++kc)
    xb[kc] = *(const f16x8*)(sXT + prow * 264 + ((kc * 32 + 8 * g) ^ swzp));

  f32x4 acc[8];
#pragma unroll
  for (int i = 0; i < 8; ++i)
#pragma unroll
    for (int j = 0; j < 4; ++j) acc[i][j] = 0.f;

#pragma unroll
  for (int kc = 0; kc < 8; ++kc)
#pragma unroll
    for (int dt = 0; dt < 8; ++dt) {
      f16x8 wa = *(const f16x8*)(Wh + (size_t)(dt * 16 + r16) * CIN + kc * 32 + 8 * g);
      acc[dt] = MFMA16(wa, xb[kc], acc[dt]);
    }

  __syncthreads();   // all waves done reading sXT (union with sO)

  // ---- epilogue: bias, fp16, transpose via LDS, 16B stores ----
#pragma unroll
  for (int dt = 0; dt < 8; ++dt) {
    f16x4 hv;
#pragma unroll
    for (int r = 0; r < 4; ++r) hv[r] = (f16)(acc[dt][r] + bias[dt * 16 + 4 * g + r]);
    *(f16x4*)(&sO[(16 * w + r16) * 136 + dt * 16 + 4 * g]) = hv;
  }
  __syncthreads();
  const int pr = tid >> 2, dseg = (tid & 3) * 32;
#pragma unroll
  for (int i = 0; i < 4; ++i) {
    f16x8 row = *(const f16x8*)(&sO[pr * 136 + dseg + 8 * i]);
    *(f16x8*)(QKT + (size_t)(p0 + pr) * DHID + dseg + 8 * i) = row;
  }
}

// ---------------------------------------------------------------------------
// Kernel 2: flash attention. Block = 32 queries, 4 waves, KV tile 128.
// QK: waves split p 4-way (8 MFMA32 each). PV: waves split c 4-way
// (16 MFMA32 each, oacc = 32 VGPR). Softmax m/l combined via LDS.
// K single-buffered via async global_load_lds issued after the QK barrier
// (PV covers its latency). Grid 1024 = 4 blocks/CU (LDS-capped at 3).
// ---------------------------------------------------------------------------
__global__ __launch_bounds__(256) void attn_kernel(
    const f16* __restrict__ QT, const f16* __restrict__ KT,
    const f16* __restrict__ Vb, float* __restrict__ out)
{
  __shared__ f16 sK[128 * 128];     // 32 KB, XOR-swizzled rows
  __shared__ f16 sP[32 * 128];      // 8 KB: P^T stored [q][p], swizzled
  __shared__ float sM[4][32], sL[4][32];

  const int tid = threadIdx.x;
  const int w = tid >> 6, lane = tid & 63;
  const int h = lane >> 5, l31 = lane & 31;
  const int x = blockIdx.x;
  const int b = (x & 7) * 4 + ((x >> 3) & 3);   // batch -> XCD locality
  const int q0 = (x >> 5) * 32;

  const f16* QTb = QT + ((size_t)b * NPIX + q0 + l31) * DHID;
  const f16* KTb = KT + (size_t)b * NPIX * DHID;
  const f16* vBb = Vb + (size_t)b * CIN * NPIX;

  f16x8 qf[8];
#pragma unroll
  for (int kt = 0; kt < 8; ++kt) qf[kt] = *(const f16x8*)(QTb + 16 * kt + 8 * h);

#define STAGE(tt)                                                              \
  {                                                                            \
    _Pragma("unroll")                                                          \
    for (int i = 0; i < 8; ++i) {                                              \
      int chunk = tid + 256 * i;                                               \
      int row = chunk >> 4, cc = chunk & 15;                                   \
      gll16(KTb + (size_t)((tt) * 128 + row) * DHID + ((cc ^ (row & 7)) * 8),  \
            &sK[chunk * 8]);                                                   \
    }                                                                          \
  }

  f32x16 oacc[2];
#pragma unroll
  for (int i = 0; i < 2; ++i)
#pragma unroll
    for (int j = 0; j < 16; ++j) oacc[i][j] = 0.f;
  float mrun = -3.0e38f, lrun = 0.f;

  const int swzq = (l31 & 7) << 4;
  char* sPq = (char*)sP + l31 * 256;

  STAGE(0);
  __syncthreads();

  for (int t = 0; t < 8; ++t) {
    // --- QK^T: wave w owns p-slice [32w,32w+32) -> S^T[32p][32q] ---
    const int r = 32 * w + l31;
    const int swzr = (l31 & 7) << 4;
    const char* sKc = (const char*)sK;
    f32x16 s;
#pragma unroll
    for (int j = 0; j < 16; ++j) s[j] = 0.f;
#pragma unroll
    for (int kt = 0; kt < 8; ++kt) {
      f16x8 kf = *(const f16x8*)(sKc + r * 256 + ((32 * kt + 16 * h) ^ swzr));
      s = MFMA32(kf, qf[kt], s);
    }

    // --- wave-partial max (q = l31 lane-local) ---
    float m_w = s[0];
#pragma unroll
    for (int j = 1; j < 16; ++j) m_w = fmaxf(m_w, s[j]);
    m_w = fmaxf(m_w, __shfl_xor(m_w, 32));
    if (lane < 32) sM[w][lane] = m_w;
    __syncthreads();                      // A: QK reads of sK done, m visible

    if (t < 7) STAGE(t + 1);              // async into sK; PV covers latency

    float m_tile = fmaxf(fmaxf(sM[0][l31], sM[1][l31]),
                         fmaxf(sM[2][l31], sM[3][l31]));
    if (__any(m_tile > mrun + 8.f)) {     // defer-max (T13); uniform across waves
      float mnew = fmaxf(mrun, m_tile);
      float sc = __expf(mrun - mnew);
      lrun *= sc; mrun = mnew;
#pragma unroll
      for (int i = 0; i < 2; ++i)
#pragma unroll
        for (int j = 0; j < 16; ++j) oacc[i][j] *= sc;
    }

    // --- P = exp(S - mrun), write P^T[q][p] chunk, partial sums ---
    float psum = 0.f;
#pragma unroll
    for (int r4 = 0; r4 < 4; ++r4) {
      f16x4 p4v;
#pragma unroll
      for (int j = 0; j < 4; ++j) {
        float pe = __expf(s[4 * r4 + j] - mrun);
        psum += pe; p4v[j] = (f16)pe;
      }
      *(f16x4*)(sPq + (((64 * w + 16 * r4 + 8 * h)) ^ swzq)) = p4v;
    }
    psum += __shfl_xor(psum, 32);
    if (lane < 32) sL[w][lane] = psum;
    __syncthreads();                      // B: P + l visible
    lrun += sL[0][l31] + sL[1][l31] + sL[2][l31] + sL[3][l31];

    // --- PV: wave w owns c-slice [64w,64w+64): O[64c][32q] ---
    f16x8 pf[8];
#pragma unroll
    for (int km = 0; km < 8; ++km)
      pf[km] = *(const f16x8*)(sPq + ((32 * km + 16 * h) ^ swzq));
#pragma unroll
    for (int ct = 0; ct < 2; ++ct) {
      const f16* vrow = vBb + (size_t)(64 * w + 32 * ct + l31) * NPIX + 128 * t + 8 * h;
#pragma unroll
      for (int km = 0; km < 8; ++km) {
        f16x8 vf = *(const f16x8*)(vrow + 16 * km);
        oacc[ct] = MFMA32(vf, pf[km], oacc[ct]);
      }
    }
    __syncthreads();                      // C: drains vmcnt (K staged) + sP reuse
  }

  // --- epilogue ---
  float inv = 1.f / lrun;
  float* ob = out + ((size_t)b * 2 * CIN + CIN) * NPIX + q0 + l31;
#pragma unroll
  for (int ct = 0; ct < 2; ++ct)
#pragma unroll
    for (int rg = 0; rg < 16; ++rg) {
      int c = 64 * w + 32 * ct + (rg & 3) + 8 * (rg >> 2) + 4 * h;
      ob[(size_t)c * NPIX] = oacc[ct][rg] * inv;
    }
}

// ---------------------------------------------------------------------------
extern "C" void kernel_launch(void* const* d_in, const int* in_sizes, int n_in,
                              void* d_out, int out_size, void* d_ws, size_t ws_size,
                              hipStream_t stream) {
  const float* left  = (const float*)d_in[0];
  const float* right = (const float*)d_in[1];
  const float* Wq    = (const float*)d_in[2];
  const float* bq    = (const float*)d_in[3];
  const float* Wk    = (const float*)d_in[4];
  const float* bk    = (const float*)d_in[5];
  float* out = (float*)d_out;
  char* ws = (char*)d_ws;

  f16* Whq = (f16*)(ws);
  f16* Whk = (f16*)(ws + 65536);
  size_t off = 131072;
  const size_t QSZ = (size_t)32 * NPIX * DHID * sizeof(f16);   // 8 MB
  f16* QT = (f16*)(ws + off); off += QSZ;
  f16* KT = (f16*)(ws + off); off += QSZ;
  f16* Vb = (f16*)(ws + off); off += (size_t)32 * CIN * NPIX * sizeof(f16);
  (void)ws_size; (void)in_sizes; (void)n_in; (void)out_size;

  wprep_kernel<<<128, 256, 0, stream>>>(Wq, Wk, Whq, Whk);

  dim3 pgrid(16, 32, 2);
  proj_kernel<<<pgrid, 256, 0, stream>>>(left, right, Whq, Whk, bq, bk,
                                         QT, KT, out, Vb);

  attn_kernel<<<1024, 256, 0, stream>>>(QT, KT, Vb, out);
}

// Round 5
// 200.090 us; speedup vs baseline: 1.1824x; 1.1824x over previous
//
#include <hip/hip_runtime.h>
#include <stdint.h>
#include <stddef.h>

#define NPIX  1024
#define DHID  128
#define CIN   256

typedef _Float16 f16;
typedef __attribute__((ext_vector_type(4))) _Float16 f16x4;
typedef __attribute__((ext_vector_type(8))) _Float16 f16x8;
typedef __attribute__((ext_vector_type(2))) __fp16 fp16x2_raw;
typedef __attribute__((ext_vector_type(4))) float f32x4;
typedef __attribute__((ext_vector_type(16))) float f32x16;

#define MFMA16(a,b,c) __builtin_amdgcn_mfma_f32_16x16x32_f16((a),(b),(c),0,0,0)
#define MFMA32(a,b,c) __builtin_amdgcn_mfma_f32_32x32x16_f16((a),(b),(c),0,0,0)

typedef const __attribute__((address_space(1))) uint32_t GU32;
typedef __attribute__((address_space(3))) uint32_t LU32;

__device__ __forceinline__ void gll16(const void* g, void* l) {
  __builtin_amdgcn_global_load_lds((GU32*)g, (LU32*)l, 16, 0, 0);
}

__device__ __forceinline__ uint32_t pkh(float a, float b) {
  fp16x2_raw p = __builtin_amdgcn_cvt_pkrtz(a, b);   // lo = a, hi = b
  return __builtin_bit_cast(uint32_t, p);
}

// ---------------------------------------------------------------------------
// Kernel 0: W fp32 -> fp16
// ---------------------------------------------------------------------------
__global__ void wprep_kernel(const float* __restrict__ Wq, const float* __restrict__ Wk,
                             f16* __restrict__ Whq, f16* __restrict__ Whk) {
  int i = blockIdx.x * 256 + threadIdx.x;
  if (i < DHID * CIN) { Whq[i] = (f16)Wq[i]; Whk[i] = (f16)Wk[i]; }
}

// ---------------------------------------------------------------------------
// Kernel 1: projection + left->out copy + V fp16 cast. Batched 8-deep loads.
// ---------------------------------------------------------------------------
__global__ __launch_bounds__(256, 3) void proj_kernel(
    const float* __restrict__ Xl, const float* __restrict__ Xr,
    const f16* __restrict__ Whq, const f16* __restrict__ Whk,
    const float* __restrict__ bq, const float* __restrict__ bk,
    f16* __restrict__ QT, f16* __restrict__ KT,
    float* __restrict__ out, f16* __restrict__ Vb)
{
  __shared__ char smem[64 * 264 * 2];        // sXT [64p][264c] f16 / sO union
  f16* sXT = (f16*)smem;
  f16* sO  = (f16*)smem;                     // [64p][136d]

  const int tid = threadIdx.x;
  const int w = tid >> 6, lane = tid & 63, g = lane >> 4, r16 = lane & 15;
  const int p0 = blockIdx.x * 64, b = blockIdx.y;
  const bool isK = (blockIdx.z != 0);

  const float* X = (isK ? Xr : Xl) + (size_t)b * CIN * NPIX;
  const f16* Wh = isK ? Whk : Whq;
  const float* bias = isK ? bk : bq;
  f16* QKT = (isK ? KT : QT) + (size_t)b * NPIX * DHID;

  const int cl = tid >> 4;            // 0..15
  const int p4 = (tid & 15) * 4;
  const int csw = (tid & 3) << 3;

  // ---- bulk stage, 2 half-passes, loads batched 8-deep ----
#pragma unroll
  for (int half = 0; half < 2; ++half) {
    f32x4 ld[8];
#pragma unroll
    for (int i = 0; i < 8; ++i) {
      int c = cl + 16 * (8 * half + i);
      ld[i] = *(const f32x4*)(X + (size_t)c * NPIX + p0 + p4);
    }
#pragma unroll
    for (int i = 0; i < 8; ++i) {
      int c = cl + 16 * (8 * half + i);
      f32x4 v = ld[i];
      if (!isK) *(f32x4*)(out + ((size_t)b * 2 * CIN + c) * NPIX + p0 + p4) = v;
      f16x4 hv = {(f16)v.x, (f16)v.y, (f16)v.z, (f16)v.w};
      if (isK) *(f16x4*)(Vb + ((size_t)b * CIN + c) * NPIX + p0 + p4) = hv;
      int cs = c ^ csw;
#pragma unroll
      for (int j = 0; j < 4; ++j) sXT[(p4 + j) * 264 + cs] = hv[j];
    }
  }
  __syncthreads();

  // ---- B-frags from sXT row, then 64 MFMA16 ----
  const int prow = 16 * w + r16;
  const int swzp = ((r16 >> 2) & 3) << 3;
  f16x8 xb[8];
#pragma unroll
  for (int kc = 0; kc < 8; ++kc)
    xb[kc] = *(const f16x8*)(sXT + prow * 264 + ((kc * 32 + 8 * g) ^ swzp));

  f32x4 acc[8];
#pragma unroll
  for (int i = 0; i < 8; ++i)
#pragma unroll
    for (int j = 0; j < 4; ++j) acc[i][j] = 0.f;

#pragma unroll
  for (int kc = 0; kc < 8; ++kc)
#pragma unroll
    for (int dt = 0; dt < 8; ++dt) {
      f16x8 wa = *(const f16x8*)(Wh + (size_t)(dt * 16 + r16) * CIN + kc * 32 + 8 * g);
      acc[dt] = MFMA16(wa, xb[kc], acc[dt]);
    }

  __syncthreads();

  // ---- epilogue: bias, fp16, transpose via LDS, 16B stores ----
#pragma unroll
  for (int dt = 0; dt < 8; ++dt) {
    f16x4 hv;
#pragma unroll
    for (int r = 0; r < 4; ++r) hv[r] = (f16)(acc[dt][r] + bias[dt * 16 + 4 * g + r]);
    *(f16x4*)(&sO[(16 * w + r16) * 136 + dt * 16 + 4 * g]) = hv;
  }
  __syncthreads();
  const int pr = tid >> 2, dseg = (tid & 3) * 32;
#pragma unroll
  for (int i = 0; i < 4; ++i) {
    f16x8 row = *(const f16x8*)(&sO[pr * 136 + dseg + 8 * i]);
    *(f16x8*)(QKT + (size_t)(p0 + pr) * DHID + dseg + 8 * i) = row;
  }
}

// ---------------------------------------------------------------------------
// Kernel 2: flash attention. 256 blocks (1/CU), 8 waves (qw 0-3 x ch 0-1),
// q-tile 128 (32 q/wave), kv-tile 64. K+V double-buffered in LDS via
// global_load_lds (pre-swizzled source), ONE barrier per tile.
// P converted S^T(C-layout) -> PV B-frags fully in-register
// (cvt_pkrtz + shfl_xor(32)).
// ---------------------------------------------------------------------------
__global__ __launch_bounds__(512, 2) void attn_kernel(
    const f16* __restrict__ QT, const f16* __restrict__ KT,
    const f16* __restrict__ Vb, float* __restrict__ out)
{
  __shared__ f16 sK[2][64 * 128];   // 2 x 16 KB
  __shared__ f16 sV[2][256 * 64];   // 2 x 32 KB

  const int tid = threadIdx.x;
  const int w = tid >> 6, lane = tid & 63;
  const int h = lane >> 5, l31 = lane & 31;
  const int qw = w & 3, ch = w >> 2;
  const int x = blockIdx.x;
  const int b = x & 31;                       // 8 q-blocks of batch b on XCD b%8
  const int q0 = (x >> 5) * 128 + qw * 32;

  const f16* QTb = QT + ((size_t)b * NPIX + q0 + l31) * DHID;
  const f16* KTb = KT + (size_t)b * NPIX * DHID;
  const f16* vBb = Vb + (size_t)b * CIN * NPIX;

  f16x8 qf[8];
#pragma unroll
  for (int kt = 0; kt < 8; ++kt) qf[kt] = *(const f16x8*)(QTb + 16 * kt + 8 * h);

#define STAGE_K(tt, bf)                                                        \
  {                                                                            \
    _Pragma("unroll")                                                          \
    for (int i_ = 0; i_ < 2; ++i_) {                                           \
      int ck_ = tid + 512 * i_;                                                \
      int rw_ = ck_ >> 4, cc_ = ck_ & 15;                                      \
      gll16(KTb + (size_t)((tt) * 64 + rw_) * DHID + ((cc_ ^ (rw_ & 7)) * 8),  \
            &sK[bf][ck_ * 8]);                                                 \
    }                                                                          \
  }
#define STAGE_V(tt, bf)                                                        \
  {                                                                            \
    _Pragma("unroll")                                                          \
    for (int i_ = 0; i_ < 4; ++i_) {                                           \
      int ck_ = tid + 512 * i_;                                                \
      int rw_ = ck_ >> 3, cc_ = ck_ & 7;                                       \
      gll16(vBb + (size_t)rw_ * NPIX + (tt) * 64 + ((cc_ ^ (rw_ & 7)) * 8),    \
            &sV[bf][ck_ * 8]);                                                 \
    }                                                                          \
  }

  f32x16 oacc[4];
#pragma unroll
  for (int i = 0; i < 4; ++i)
#pragma unroll
    for (int j = 0; j < 16; ++j) oacc[i][j] = 0.f;
  float mrun = -3.0e38f, lrun = 0.f;

  union PF { uint32_t u[4]; f16x8 v; };

  STAGE_K(0, 0);
  STAGE_V(0, 0);
  __syncthreads();

  for (int t = 0; t < 16; ++t) {
    const int cur = t & 1;
    if (t < 15) { STAGE_K(t + 1, cur ^ 1); STAGE_V(t + 1, cur ^ 1); }

    // --- QK^T: S^T[64p][32q] as 2 C-tiles; A=K from LDS, B=Q regs ---
    f32x16 s0, s1;
#pragma unroll
    for (int j = 0; j < 16; ++j) { s0[j] = 0.f; s1[j] = 0.f; }
    const char* kb = (const char*)&sK[cur][0];
    const int sw8 = l31 & 7;
#pragma unroll
    for (int kt = 0; kt < 8; ++kt) {
      f16x8 k0 = *(const f16x8*)(kb + l31 * 256 + (((2 * kt + h) ^ sw8) << 4));
      f16x8 k1 = *(const f16x8*)(kb + (32 + l31) * 256 + (((2 * kt + h) ^ sw8) << 4));
      s0 = MFMA32(k0, qf[kt], s0);
      s1 = MFMA32(k1, qf[kt], s1);
    }

    // --- online softmax, per-wave independent (q = l31, halves via shfl) ---
    float pmax = s0[0];
#pragma unroll
    for (int j = 0; j < 16; ++j) { pmax = fmaxf(pmax, s0[j]); pmax = fmaxf(pmax, s1[j]); }
    pmax = fmaxf(pmax, __shfl_xor(pmax, 32));
    if (__any(pmax > mrun + 8.f)) {        // defer-max (T13)
      float mnew = fmaxf(mrun, pmax);
      float sc = __expf(mrun - mnew);
      mrun = mnew; lrun *= sc;
#pragma unroll
      for (int i = 0; i < 4; ++i)
#pragma unroll
        for (int j = 0; j < 16; ++j) oacc[i][j] *= sc;
    }
    float psum = 0.f;
#pragma unroll
    for (int j = 0; j < 16; ++j) {
      s0[j] = __expf(s0[j] - mrun); psum += s0[j];
      s1[j] = __expf(s1[j] - mrun); psum += s1[j];
    }
    psum += __shfl_xor(psum, 32);
    lrun += psum;

    // --- in-register P -> PV B-frags (pack + cross-half shfl) ---
    // C-layout: reg r of half h' holds p = (r&3) + 8*(r>>2) + 4h' (+32*pt).
    // B-frag(pk) elem j: reg 4*(2pk+h)+(j&3), half h' = j>>2.
    uint32_t u0[8], u1[8];
#pragma unroll
    for (int qd = 0; qd < 4; ++qd) {
      u0[qd]     = pkh(s0[4 * qd], s0[4 * qd + 1]);
      u1[qd]     = pkh(s0[4 * qd + 2], s0[4 * qd + 3]);
      u0[4 + qd] = pkh(s1[4 * qd], s1[4 * qd + 1]);
      u1[4 + qd] = pkh(s1[4 * qd + 2], s1[4 * qd + 3]);
    }
    PF pf[4];
#pragma unroll
    for (int pk = 0; pk < 4; ++pk) {
      uint32_t A = u0[2 * pk], B = u0[2 * pk + 1];
      uint32_t C = u1[2 * pk], D = u1[2 * pk + 1];
      uint32_t sA = (uint32_t)__shfl_xor((int)A, 32);
      uint32_t sB = (uint32_t)__shfl_xor((int)B, 32);
      uint32_t sC = (uint32_t)__shfl_xor((int)C, 32);
      uint32_t sD = (uint32_t)__shfl_xor((int)D, 32);
      pf[pk].u[0] = h ? sB : A;   // j0,1 (from half 0)
      pf[pk].u[1] = h ? sD : C;   // j2,3 (from half 0)
      pf[pk].u[2] = h ? B : sA;   // j4,5 (from half 1)
      pf[pk].u[3] = h ? D : sC;   // j6,7 (from half 1)
    }

    // --- PV: wave's 128-c half; A=V from LDS, B=pf; 16 MFMA32 ---
    const char* vbp = (const char*)&sV[cur][0];
#pragma unroll
    for (int ct = 0; ct < 4; ++ct) {
      int row = 128 * ch + 32 * ct + l31;
#pragma unroll
      for (int pk = 0; pk < 4; ++pk) {
        f16x8 vf = *(const f16x8*)(vbp + row * 128 + (((2 * pk + h) ^ sw8) << 4));
        oacc[ct] = MFMA32(vf, pf[pk].v, oacc[ct]);
      }
    }
    __syncthreads();   // reads of cur done + stage of cur^1 complete
  }

  // --- epilogue: normalize + scatter to out[b][256+c][q] ---
  float inv = 1.f / lrun;
  float* ob = out + ((size_t)b * 2 * CIN + CIN + 128 * ch) * NPIX + q0 + l31;
#pragma unroll
  for (int ct = 0; ct < 4; ++ct)
#pragma unroll
    for (int rg = 0; rg < 16; ++rg) {
      int c = 32 * ct + (rg & 3) + 8 * (rg >> 2) + 4 * h;
      ob[(size_t)c * NPIX] = oacc[ct][rg] * inv;
    }
}

// ---------------------------------------------------------------------------
extern "C" void kernel_launch(void* const* d_in, const int* in_sizes, int n_in,
                              void* d_out, int out_size, void* d_ws, size_t ws_size,
                              hipStream_t stream) {
  const float* left  = (const float*)d_in[0];
  const float* right = (const float*)d_in[1];
  const float* Wq    = (const float*)d_in[2];
  const float* bq    = (const float*)d_in[3];
  const float* Wk    = (const float*)d_in[4];
  const float* bk    = (const float*)d_in[5];
  float* out = (float*)d_out;
  char* ws = (char*)d_ws;

  f16* Whq = (f16*)(ws);
  f16* Whk = (f16*)(ws + 65536);
  size_t off = 131072;
  const size_t QSZ = (size_t)32 * NPIX * DHID * sizeof(f16);   // 8 MB
  f16* QT = (f16*)(ws + off); off += QSZ;
  f16* KT = (f16*)(ws + off); off += QSZ;
  f16* Vb = (f16*)(ws + off); off += (size_t)32 * CIN * NPIX * sizeof(f16);
  (void)ws_size; (void)in_sizes; (void)n_in; (void)out_size;

  wprep_kernel<<<128, 256, 0, stream>>>(Wq, Wk, Whq, Whk);

  dim3 pgrid(16, 32, 2);
  proj_kernel<<<pgrid, 256, 0, stream>>>(left, right, Whq, Whk, bq, bk,
                                         QT, KT, out, Vb);

  attn_kernel<<<256, 512, 0, stream>>>(QT, KT, Vb, out);
}